// Round 5
// baseline (693.716 us; speedup 1.0000x reference)
//
#include <hip/hip_runtime.h>
#include <hip/hip_bf16.h>

#define NTOK 4096
#define DEMB 1024
#define NH   8
#define DH   128
#define CWIN 256
#define QKVW 384
#define SCALE 0.08838834764831845f   // 1/sqrt(128)
#define QT 8
#define NCH 34                        // 16-key chunks covering the <=520-wide band

typedef __attribute__((ext_vector_type(8))) short short8;
typedef __attribute__((ext_vector_type(4))) float floatx4;

__device__ __forceinline__ short8 pack8(float4 a, float4 b) {
    union { __hip_bfloat16 h[8]; short8 v; } o;
    o.h[0] = __float2bfloat16(a.x); o.h[1] = __float2bfloat16(a.y);
    o.h[2] = __float2bfloat16(a.z); o.h[3] = __float2bfloat16(a.w);
    o.h[4] = __float2bfloat16(b.x); o.h[5] = __float2bfloat16(b.y);
    o.h[6] = __float2bfloat16(b.z); o.h[7] = __float2bfloat16(b.w);
    return o.v;
}

// ---------------- weight prep (once per call) ----------------
__global__ void pack_wqkv(const float* __restrict__ Wq, const float* __restrict__ Wk,
                          const float* __restrict__ Wvd, __hip_bfloat16* __restrict__ dst) {
    size_t base = ((size_t)blockIdx.x * 256 + threadIdx.x) * 8;
    int k = (int)(base & 1023);
    int rh = (int)(base >> 10);
    int h = rh / QKVW;
    int row = rh - h * QKVW;
    const float* srcs[3] = {Wq, Wk, Wvd};
    const float* s = srcs[row >> 7] + (((size_t)h * DH + (row & 127)) << 10) + k;
    *(short8*)(dst + base) = pack8(*(const float4*)s, *(const float4*)(s + 4));
}

__global__ void pack_wvu(const float* __restrict__ Wvu, __hip_bfloat16* __restrict__ dst) {
    size_t base = ((size_t)blockIdx.x * 256 + threadIdx.x) * 8;
    *(short8*)(dst + base) = pack8(*(const float4*)(Wvu + base), *(const float4*)(Wvu + base + 4));
}

// ---------------- stage 0: e = x (+ bf16 mirror for head-0 qkv) -----------
__global__ void init_e(const float4* __restrict__ x, float4* __restrict__ e,
                       __hip_bfloat16* __restrict__ ebf) {
    int i = blockIdx.x * 256 + threadIdx.x;
    float4 v = x[i];
    e[i] = v;
    union { __hip_bfloat16 h[4]; uint2 u; } p;
    p.h[0] = __float2bfloat16(v.x); p.h[1] = __float2bfloat16(v.y);
    p.h[2] = __float2bfloat16(v.z); p.h[3] = __float2bfloat16(v.w);
    *(uint2*)(ebf + (size_t)i * 4) = p.u;
}

// ---------------- head-0 qkv GEMM: emits Q (scaled), K, V^T ---------------
__global__ __launch_bounds__(256) void qkv_gemm_mfma(const __hip_bfloat16* __restrict__ A,
                                                     const __hip_bfloat16* __restrict__ B,
                                                     __hip_bfloat16* __restrict__ Qb,
                                                     __hip_bfloat16* __restrict__ Kb,
                                                     __hip_bfloat16* __restrict__ Vtb) {
    constexpr int K = DEMB;
    constexpr int LDK = 40;
    const int c0 = blockIdx.x * 64, r0 = blockIdx.y * 64;
    const int tid = threadIdx.x;
    const int wave = tid >> 6, lane = tid & 63;
    const int wr = (wave >> 1) * 32, wc = (wave & 1) * 32;
    const int frow = lane & 15, kgrp = (lane >> 4) * 8;
    const int quad = lane >> 4;
    const int sr = tid >> 2, sk = (tid & 3) * 8;

    __shared__ __hip_bfloat16 As[64 * LDK];
    __shared__ __hip_bfloat16 Bs[64 * LDK];

    floatx4 acc[2][2] = {};

    for (int k0 = 0; k0 < K; k0 += 32) {
        __syncthreads();
        *(short8*)(As + sr * LDK + sk) = *(const short8*)(A + (size_t)(r0 + sr) * K + k0 + sk);
        *(short8*)(Bs + sr * LDK + sk) = *(const short8*)(B + (size_t)(c0 + sr) * K + k0 + sk);
        __syncthreads();
        short8 a0 = *(const short8*)(As + (wr + frow) * LDK + kgrp);
        short8 a1 = *(const short8*)(As + (wr + 16 + frow) * LDK + kgrp);
        short8 b0 = *(const short8*)(Bs + (wc + frow) * LDK + kgrp);
        short8 b1 = *(const short8*)(Bs + (wc + 16 + frow) * LDK + kgrp);
        acc[0][0] = __builtin_amdgcn_mfma_f32_16x16x32_bf16(a0, b0, acc[0][0], 0, 0, 0);
        acc[0][1] = __builtin_amdgcn_mfma_f32_16x16x32_bf16(a0, b1, acc[0][1], 0, 0, 0);
        acc[1][0] = __builtin_amdgcn_mfma_f32_16x16x32_bf16(a1, b0, acc[1][0], 0, 0, 0);
        acc[1][1] = __builtin_amdgcn_mfma_f32_16x16x32_bf16(a1, b1, acc[1][1], 0, 0, 0);
    }

    #pragma unroll
    for (int i = 0; i < 2; i++)
        #pragma unroll
        for (int j = 0; j < 2; j++) {
            int col = c0 + wc + j * 16 + frow;
            int row0 = r0 + wr + i * 16 + quad * 4;
            if (col < DH) {
                #pragma unroll
                for (int r = 0; r < 4; r++)
                    Qb[(size_t)(row0 + r) * DH + col] = __float2bfloat16(acc[i][j][r] * SCALE);
            } else if (col < 2 * DH) {
                #pragma unroll
                for (int r = 0; r < 4; r++)
                    Kb[(size_t)(row0 + r) * DH + col - DH] = __float2bfloat16(acc[i][j][r]);
            } else {
                union { __hip_bfloat16 h[4]; uint2 u; } p;
                #pragma unroll
                for (int r = 0; r < 4; r++) p.h[r] = __float2bfloat16(acc[i][j][r]);
                *(uint2*)(Vtb + (size_t)(col - 2 * DH) * NTOK + row0) = p.u;
            }
        }
}

// ---------------- fused head kernel -----------------------------------
// QT=8: grid 512, 8 waves (512 thr), ~28 KB LDS -> TWO independent blocks
// per CU (R3: all waves in one barrier group stalled 85% of cycles).
// Max-subtraction RESTORED (R4 NaN): mean drift (+1/head from the "+m"
// norm term) grows sigma_s ~ 0.41*(h^2+h) => |s| can exceed 88 by head 7;
// expf overflows without the max. 5 barriers/head (Q from L2, no Q-stage
// barrier; sum barrier doubles as Pb-ready barrier).
// M=16 MFMA with 8 q-rows: A-rows 8-15 duplicated via (fr&7) on all
// A-fragment reads => C-rows 8-15 are bit-exact dups of rows 0-7; all
// global/stats writes guarded to quads 0-1 (wr_ok). Reductions (shfl
// masks 1..8) never cross 16-lane quad groups, so dups stay contained.
// OOB band-edge fragment reads land in adjacent ws buffers: finite bf16,
// multiplied by p=0.
__global__ __launch_bounds__(512, 4) void attn_head(const __hip_bfloat16* __restrict__ Qb,
                                                    const __hip_bfloat16* __restrict__ Kb,
                                                    const __hip_bfloat16* __restrict__ Vtb,
                                                    __hip_bfloat16* __restrict__ Qn,
                                                    __hip_bfloat16* __restrict__ Kn,
                                                    __hip_bfloat16* __restrict__ Vtn,
                                                    const __hip_bfloat16* __restrict__ Wqkv_nxt,
                                                    const __hip_bfloat16* __restrict__ Wvu,
                                                    float* __restrict__ e,
                                                    float* __restrict__ out_final) {
    // XCD-chunked swizzle: 512 blocks, XCD k gets a contiguous run of 64
    // q-tiles so the +-CWIN band and e-slice stay in its 4MB L2.
    const int tile = ((blockIdx.x & 7) << 6) | (blockIdx.x >> 3);
    const int q0 = tile * QT;
    const int tid = threadIdx.x;
    const int wave = tid >> 6, lane = tid & 63;       // wave in [0,8)
    const int fr = lane & 15, kg = (lane >> 4) * 8;
    const int quad = lane >> 4;
    const int frh = fr & 7;               // dup A-row index
    const int rq = (quad & 1) * 4;        // dup C-row base (0 or 4)
    const bool wr_ok = (quad < 2);        // quads 0-1 own the 8 real rows
    const bool last = (out_final != nullptr);

    __shared__ alignas(16) __hip_bfloat16 Us[QT][DH + 8];      // u rows (attn out)
    __shared__ alignas(16) __hip_bfloat16 Pb[QT][NCH * 16 + 8];
    __shared__ alignas(16) __hip_bfloat16 Ebs[QT][DEMB + 8];   // bf16 res rows (A for qkv tail)
    __shared__ float statsA[QT][8];
    __shared__ float statsB[QT][8];

    // ---- e prefetch: 8 rows, wave owns cols [128w,128w+128); written by the
    // SAME tile in the previous launch -> ready at t=0, latency hides here.
    floatx4 eo8[8];
    #pragma unroll
    for (int n0 = 0; n0 < 8; n0++) {
        int col = wave * 128 + n0 * 16 + fr;
        #pragma unroll
        for (int r = 0; r < 4; r++)
            eo8[n0][r] = e[(size_t)(q0 + rq + r) * DEMB + col];
    }

    // ---- Q fragments straight from L2 (pre-scaled), dup rows via frh ------
    short8 af[4];
    #pragma unroll
    for (int kc = 0; kc < 4; kc++)
        af[kc] = *(const short8*)(Qb + (size_t)(q0 + frh) * DH + kc * 32 + kg);

    const int kstart = max(q0 - CWIN, 0);
    const int kend   = min(q0 + QT - 1 + CWIN + 1, NTOK);
    const int nch = (wave < 2) ? 5 : 4;   // chunks ch = wave + 8t, ch < 34

    // ---- scores: wave's chunks, K fragments straight from L2 -------------
    floatx4 sreg[5];
    #pragma unroll
    for (int t = 0; t < 5; t++) {
        if (t >= nch) break;
        int ch = wave + 8 * t;
        const __hip_bfloat16* krow = Kb + (size_t)(kstart + ch * 16 + fr) * DH;
        floatx4 s = {};
        #pragma unroll
        for (int kc = 0; kc < 4; kc++)
            s = __builtin_amdgcn_mfma_f32_16x16x32_bf16(af[kc],
                    *(const short8*)(krow + kc * 32 + kg), s, 0, 0, 0);
        sreg[t] = s;
    }

    // ---- band mask + per-row max ------------------------------------------
    float pmax[4] = {-1e30f, -1e30f, -1e30f, -1e30f};
    #pragma unroll
    for (int t = 0; t < 5; t++) {
        if (t >= nch) break;
        int tcol = kstart + (wave + 8 * t) * 16 + fr;
        #pragma unroll
        for (int r = 0; r < 4; r++) {
            int qg = q0 + rq + r;
            bool ok = (tcol < kend) && (tcol >= qg - CWIN) && (tcol < qg + CWIN);
            float v = ok ? sreg[t][r] : -1e30f;
            sreg[t][r] = v;
            pmax[r] = fmaxf(pmax[r], v);
        }
    }
    #pragma unroll
    for (int mm = 1; mm <= 8; mm <<= 1)
        #pragma unroll
        for (int r = 0; r < 4; r++) pmax[r] = fmaxf(pmax[r], __shfl_xor(pmax[r], mm, 64));
    if (fr == 0 && wr_ok)
        #pragma unroll
        for (int r = 0; r < 4; r++) statsA[rq + r][wave] = pmax[r];
    __syncthreads();                                   // bar1: row maxes

    float M[4];
    #pragma unroll
    for (int r = 0; r < 4; r++) {
        float m = statsA[rq + r][0];
        #pragma unroll
        for (int w = 1; w < 8; w++) m = fmaxf(m, statsA[rq + r][w]);
        M[r] = m;
    }

    // ---- exp(s - M) -> Pb (A-layout), row sums ----------------------------
    float psum[4] = {};
    #pragma unroll
    for (int t = 0; t < 5; t++) {
        if (t >= nch) break;
        int colb = (wave + 8 * t) * 16 + fr;
        #pragma unroll
        for (int r = 0; r < 4; r++) {
            float p = __expf(sreg[t][r] - M[r]);
            psum[r] += p;
            if (wr_ok) Pb[rq + r][colb] = __float2bfloat16(p);
        }
    }
    #pragma unroll
    for (int mm = 1; mm <= 8; mm <<= 1)
        #pragma unroll
        for (int r = 0; r < 4; r++) psum[r] += __shfl_xor(psum[r], mm, 64);
    if (fr == 0 && wr_ok)
        #pragma unroll
        for (int r = 0; r < 4; r++) statsB[rq + r][wave] = psum[r];
    __syncthreads();                                   // bar2: Pb + sums

    float linv[4];
    #pragma unroll
    for (int r = 0; r < 4; r++) {
        float s = statsB[rq + r][0];
        #pragma unroll
        for (int w = 1; w < 8; w++) s += statsB[rq + r][w];
        linv[r] = 1.0f / s;
    }

    // ---- PV: wave owns dims [16w,16w+16); Vt fragments from L2 ------------
    {
        floatx4 Of = {};
        #pragma unroll
        for (int kc = 0; kc < NCH / 2; kc++) {
            short8 pf = *(const short8*)&Pb[frh][kc * 32 + kg];
            const __hip_bfloat16* vrow = Vtb + (size_t)(wave * 16 + fr) * NTOK
                                       + kstart + kc * 32 + kg;
            Of = __builtin_amdgcn_mfma_f32_16x16x32_bf16(pf, *(const short8*)vrow, Of, 0, 0, 0);
        }
        if (wr_ok) {
            int col = wave * 16 + fr;
            #pragma unroll
            for (int r = 0; r < 4; r++)
                Us[rq + r][col] = __float2bfloat16(Of[r] * linv[r]);
        }
    }
    __syncthreads();                                   // bar3: u rows ready
    short8 af2[4];
    #pragma unroll
    for (int kc = 0; kc < 4; kc++) af2[kc] = *(const short8*)&Us[frh][kc * 32 + kg];

    // ---- out-proj: wave owns cols [128w,128w+128); Wvu from L2 ------------
    floatx4 accd[8] = {};
    #pragma unroll
    for (int n0 = 0; n0 < 8; n0++) {
        const __hip_bfloat16* wrow = Wvu + ((size_t)(wave * 128 + n0 * 16 + fr) << 7);
        #pragma unroll
        for (int kc = 0; kc < 4; kc++)
            accd[n0] = __builtin_amdgcn_mfma_f32_16x16x32_bf16(af2[kc],
                           *(const short8*)(wrow + kc * 32 + kg), accd[n0], 0, 0, 0);
    }

    // ---- norm stats (e rows already in registers) -------------------------
    float s1[4] = {}, s2[4] = {};
    #pragma unroll
    for (int n0 = 0; n0 < 8; n0++) {
        #pragma unroll
        for (int r = 0; r < 4; r++) {
            float od = eo8[n0][r] + accd[n0][r];
            s1[r] += od; s2[r] += od * od;
        }
    }
    #pragma unroll
    for (int mm = 1; mm <= 8; mm <<= 1)
        #pragma unroll
        for (int r = 0; r < 4; r++) {
            s1[r] += __shfl_xor(s1[r], mm, 64);
            s2[r] += __shfl_xor(s2[r], mm, 64);
        }
    if (fr == 0 && wr_ok)
        #pragma unroll
        for (int r = 0; r < 4; r++) {
            statsA[rq + r][wave] = s1[r];
            statsB[rq + r][wave] = s2[r];
        }
    __syncthreads();                                   // bar4: norm stats

    float im0[4], mm_[4], isd[4];
    #pragma unroll
    for (int r = 0; r < 4; r++) {
        float S1 = statsA[rq + r][0], S2 = statsB[rq + r][0];
        #pragma unroll
        for (int w = 1; w < 8; w++) { S1 += statsA[rq + r][w]; S2 += statsB[rq + r][w]; }
        float m0 = S1 * (1.0f / DEMB);
        float iv = 1.0f / m0;
        float m  = m0 * iv;                        // mean(out/m0) ~ 1
        float st = S1 * iv;
        float var = (S2 * iv * iv - st * st * (1.0f / DEMB)) * (1.0f / (DEMB - 1));
        im0[r] = iv; mm_[r] = m; isd[r] = rsqrtf(var);
    }

    // ---- final residual+norm; write e (or out); stage bf16 res for tail ---
    #pragma unroll
    for (int n0 = 0; n0 < 8; n0++) {
        int col = wave * 128 + n0 * 16 + fr;
        #pragma unroll
        for (int r = 0; r < 4; r++) {
            float ev = eo8[n0][r];
            float t = (ev + accd[n0][r]) * im0[r];
            float res = ev + (t - mm_[r]) * isd[r] + mm_[r];
            if (wr_ok) {
                size_t idx = (size_t)(q0 + rq + r) * DEMB + col;
                if (last) {
                    out_final[idx] = res * 0.125f;
                } else {
                    e[idx] = res;
                    Ebs[rq + r][col] = __float2bfloat16(res);
                }
            }
        }
    }

    // ---- fused next-head QKV: 24 N-tiles over 8 waves (3 each) ------------
    if (!last) {
        __syncthreads();               // bar5: Ebs complete
        floatx4 acc3[3] = {};
        const int n0t = 3 * wave;
        const __hip_bfloat16* wbase = Wqkv_nxt + (size_t)(n0t * 16 + fr) * DEMB + kg;
        #pragma unroll 8
        for (int kc = 0; kc < 32; kc++) {
            short8 a = *(const short8*)&Ebs[frh][kc * 32 + kg];
            #pragma unroll
            for (int t = 0; t < 3; t++)
                acc3[t] = __builtin_amdgcn_mfma_f32_16x16x32_bf16(a,
                              *(const short8*)(wbase + (size_t)t * 16 * DEMB + kc * 32),
                              acc3[t], 0, 0, 0);
        }
        if (wr_ok) {
            const int row0 = q0 + rq;
            #pragma unroll
            for (int t = 0; t < 3; t++) {
                int n = n0t + t;
                if (n < 8) {               // Q, pre-scaled
                    int col = n * 16 + fr;
                    #pragma unroll
                    for (int rr = 0; rr < 4; rr++)
                        Qn[(size_t)(row0 + rr) * DH + col] = __float2bfloat16(acc3[t][rr] * SCALE);
                } else if (n < 16) {       // K
                    int col = (n - 8) * 16 + fr;
                    #pragma unroll
                    for (int rr = 0; rr < 4; rr++)
                        Kn[(size_t)(row0 + rr) * DH + col] = __float2bfloat16(acc3[t][rr]);
                } else {                   // V^T
                    int d = (n - 16) * 16 + fr;
                    union { __hip_bfloat16 h[4]; uint2 u; } p;
                    #pragma unroll
                    for (int rr = 0; rr < 4; rr++) p.h[rr] = __float2bfloat16(acc3[t][rr]);
                    *(uint2*)(Vtn + (size_t)d * NTOK + row0) = p.u;
                }
            }
        }
    }
}

extern "C" void kernel_launch(void* const* d_in, const int* in_sizes, int n_in,
                              void* d_out, int out_size, void* d_ws, size_t ws_size,
                              hipStream_t stream) {
    const float* x   = (const float*)d_in[0];
    const float* Wq  = (const float*)d_in[1];
    const float* Wk  = (const float*)d_in[2];
    const float* Wvd = (const float*)d_in[3];
    const float* Wvu = (const float*)d_in[4];

    char* ws = (char*)d_ws;
    float* e = (float*)ws;                                              // 16 MB
    __hip_bfloat16* ebf   = (__hip_bfloat16*)(ws + (16u << 20));        //  8 MB (head-0 prologue only)
    __hip_bfloat16* Qb[2] = {(__hip_bfloat16*)(ws + (24u << 20)),
                             (__hip_bfloat16*)(ws + (27u << 20))};      //  1 MB each
    __hip_bfloat16* Kb[2] = {(__hip_bfloat16*)(ws + (25u << 20)),
                             (__hip_bfloat16*)(ws + (28u << 20))};
    __hip_bfloat16* Vt[2] = {(__hip_bfloat16*)(ws + (26u << 20)),
                             (__hip_bfloat16*)(ws + (29u << 20))};
    __hip_bfloat16* wqkvb = (__hip_bfloat16*)(ws + (30u << 20));        //  6 MB
    __hip_bfloat16* wvub  = (__hip_bfloat16*)(ws + (36u << 20));        //  2 MB  -> 38 MB

    pack_wqkv<<<NH * QKVW * DEMB / 8 / 256, 256, 0, stream>>>(Wq, Wk, Wvd, wqkvb);
    pack_wvu<<<NH * DEMB * DH / 8 / 256, 256, 0, stream>>>(Wvu, wvub);
    init_e<<<NTOK * DEMB / 4 / 256, 256, 0, stream>>>((const float4*)x, (float4*)e, ebf);

    qkv_gemm_mfma<<<dim3(QKVW / 64, NTOK / 64), 256, 0, stream>>>(
        ebf, wqkvb, Qb[0], Kb[0], Vt[0]);

    for (int h = 0; h < NH; h++) {
        int cur = h & 1, nxt = 1 - cur;
        attn_head<<<NTOK / QT, 512, 0, stream>>>(
            Qb[cur], Kb[cur], Vt[cur],
            Qb[nxt], Kb[nxt], Vt[nxt],
            wqkvb + (size_t)((h + 1 < NH) ? h + 1 : 0) * QKVW * DEMB,
            wvub + (size_t)h * DEMB * DH, e,
            (h == NH - 1) ? (float*)d_out : nullptr);
    }
}

// Round 6
// 445.430 us; speedup vs baseline: 1.5574x; 1.5574x over previous
//
#include <hip/hip_runtime.h>
#include <hip/hip_bf16.h>

#define NTOK 4096
#define DEMB 1024
#define NH   8
#define DH   128
#define CWIN 256
#define QKVW 384
#define SCALE 0.08838834764831845f   // 1/sqrt(128)
#define QT 16
#define NCH 34                        // 16-key chunks covering the <=528-wide band

typedef __attribute__((ext_vector_type(8))) short short8;
typedef __attribute__((ext_vector_type(4))) float floatx4;

__device__ __forceinline__ short8 pack8(float4 a, float4 b) {
    union { __hip_bfloat16 h[8]; short8 v; } o;
    o.h[0] = __float2bfloat16(a.x); o.h[1] = __float2bfloat16(a.y);
    o.h[2] = __float2bfloat16(a.z); o.h[3] = __float2bfloat16(a.w);
    o.h[4] = __float2bfloat16(b.x); o.h[5] = __float2bfloat16(b.y);
    o.h[6] = __float2bfloat16(b.z); o.h[7] = __float2bfloat16(b.w);
    return o.v;
}

// ---------------- weight prep (once per call) ----------------
__global__ void pack_wqkv(const float* __restrict__ Wq, const float* __restrict__ Wk,
                          const float* __restrict__ Wvd, __hip_bfloat16* __restrict__ dst) {
    size_t base = ((size_t)blockIdx.x * 256 + threadIdx.x) * 8;
    int k = (int)(base & 1023);
    int rh = (int)(base >> 10);
    int h = rh / QKVW;
    int row = rh - h * QKVW;
    const float* srcs[3] = {Wq, Wk, Wvd};
    const float* s = srcs[row >> 7] + (((size_t)h * DH + (row & 127)) << 10) + k;
    *(short8*)(dst + base) = pack8(*(const float4*)s, *(const float4*)(s + 4));
}

__global__ void pack_wvu(const float* __restrict__ Wvu, __hip_bfloat16* __restrict__ dst) {
    size_t base = ((size_t)blockIdx.x * 256 + threadIdx.x) * 8;
    *(short8*)(dst + base) = pack8(*(const float4*)(Wvu + base), *(const float4*)(Wvu + base + 4));
}

// ---------------- stage 0: e = x (+ bf16 mirror for head-0 qkv) -----------
__global__ void init_e(const float4* __restrict__ x, float4* __restrict__ e,
                       __hip_bfloat16* __restrict__ ebf) {
    int i = blockIdx.x * 256 + threadIdx.x;
    float4 v = x[i];
    e[i] = v;
    union { __hip_bfloat16 h[4]; uint2 u; } p;
    p.h[0] = __float2bfloat16(v.x); p.h[1] = __float2bfloat16(v.y);
    p.h[2] = __float2bfloat16(v.z); p.h[3] = __float2bfloat16(v.w);
    *(uint2*)(ebf + (size_t)i * 4) = p.u;
}

// ---------------- head-0 qkv GEMM: emits Q (scaled), K, V^T ---------------
__global__ __launch_bounds__(256) void qkv_gemm_mfma(const __hip_bfloat16* __restrict__ A,
                                                     const __hip_bfloat16* __restrict__ B,
                                                     __hip_bfloat16* __restrict__ Qb,
                                                     __hip_bfloat16* __restrict__ Kb,
                                                     __hip_bfloat16* __restrict__ Vtb) {
    constexpr int K = DEMB;
    constexpr int LDK = 40;
    const int c0 = blockIdx.x * 64, r0 = blockIdx.y * 64;
    const int tid = threadIdx.x;
    const int wave = tid >> 6, lane = tid & 63;
    const int wr = (wave >> 1) * 32, wc = (wave & 1) * 32;
    const int frow = lane & 15, kgrp = (lane >> 4) * 8;
    const int quad = lane >> 4;
    const int sr = tid >> 2, sk = (tid & 3) * 8;

    __shared__ __hip_bfloat16 As[64 * LDK];
    __shared__ __hip_bfloat16 Bs[64 * LDK];

    floatx4 acc[2][2] = {};

    for (int k0 = 0; k0 < K; k0 += 32) {
        __syncthreads();
        *(short8*)(As + sr * LDK + sk) = *(const short8*)(A + (size_t)(r0 + sr) * K + k0 + sk);
        *(short8*)(Bs + sr * LDK + sk) = *(const short8*)(B + (size_t)(c0 + sr) * K + k0 + sk);
        __syncthreads();
        short8 a0 = *(const short8*)(As + (wr + frow) * LDK + kgrp);
        short8 a1 = *(const short8*)(As + (wr + 16 + frow) * LDK + kgrp);
        short8 b0 = *(const short8*)(Bs + (wc + frow) * LDK + kgrp);
        short8 b1 = *(const short8*)(Bs + (wc + 16 + frow) * LDK + kgrp);
        acc[0][0] = __builtin_amdgcn_mfma_f32_16x16x32_bf16(a0, b0, acc[0][0], 0, 0, 0);
        acc[0][1] = __builtin_amdgcn_mfma_f32_16x16x32_bf16(a0, b1, acc[0][1], 0, 0, 0);
        acc[1][0] = __builtin_amdgcn_mfma_f32_16x16x32_bf16(a1, b0, acc[1][0], 0, 0, 0);
        acc[1][1] = __builtin_amdgcn_mfma_f32_16x16x32_bf16(a1, b1, acc[1][1], 0, 0, 0);
    }

    #pragma unroll
    for (int i = 0; i < 2; i++)
        #pragma unroll
        for (int j = 0; j < 2; j++) {
            int col = c0 + wc + j * 16 + frow;
            int row0 = r0 + wr + i * 16 + quad * 4;
            if (col < DH) {
                #pragma unroll
                for (int r = 0; r < 4; r++)
                    Qb[(size_t)(row0 + r) * DH + col] = __float2bfloat16(acc[i][j][r] * SCALE);
            } else if (col < 2 * DH) {
                #pragma unroll
                for (int r = 0; r < 4; r++)
                    Kb[(size_t)(row0 + r) * DH + col - DH] = __float2bfloat16(acc[i][j][r]);
            } else {
                union { __hip_bfloat16 h[4]; uint2 u; } p;
                #pragma unroll
                for (int r = 0; r < 4; r++) p.h[r] = __float2bfloat16(acc[i][j][r]);
                *(uint2*)(Vtb + (size_t)(col - 2 * DH) * NTOK + row0) = p.u;
            }
        }
}

// ---------------- fused head kernel -----------------------------------
// QT=16, grid 256 (1 block/CU), 8 waves. R3/R5 established: runtime ~
// (VMEM instrs per SIMD) x ~250cyc, independent of occupancy -> the wall
// is per-wave MLP ~1 (VGPR_Count 60: compiler kept nothing in flight).
// This version register-pipelines every MFMA phase under a 256-VGPR cap
// (__launch_bounds__(512,2); grid=256 -> 1 block/CU either way):
//   scores: ALL K fragments preloaded (16-20 in flight)
//   PV:     8-deep Vt fragment ring
//   outproj:3-deep Wvu group ring (4 frags/group)
//   qkvtail:4-deep Wqkv group ring (3 frags/group)
// Max-subtraction kept (R4: mean drift => |s| can exceed 88 by head 7).
// Q fragments direct from L2 (no stage barrier); 5 barriers/head.
// OOB band-edge fragment reads land in adjacent ws buffers: finite bf16,
// multiplied by p=0.
__global__ __launch_bounds__(512, 2) void attn_head(const __hip_bfloat16* __restrict__ Qb,
                                                    const __hip_bfloat16* __restrict__ Kb,
                                                    const __hip_bfloat16* __restrict__ Vtb,
                                                    __hip_bfloat16* __restrict__ Qn,
                                                    __hip_bfloat16* __restrict__ Kn,
                                                    __hip_bfloat16* __restrict__ Vtn,
                                                    const __hip_bfloat16* __restrict__ Wqkv_nxt,
                                                    const __hip_bfloat16* __restrict__ Wvu,
                                                    float* __restrict__ e,
                                                    float* __restrict__ out_final) {
    // XCD-chunked swizzle: XCD k gets a contiguous run of 32 q-tiles so the
    // +-CWIN band and e-slice stay in its 4MB L2.
    const int tile = ((blockIdx.x & 7) << 5) | (blockIdx.x >> 3);
    const int q0 = tile * QT;
    const int tid = threadIdx.x;
    const int wave = tid >> 6, lane = tid & 63;       // wave in [0,8)
    const int fr = lane & 15, kg = (lane >> 4) * 8;
    const int quad = lane >> 4;
    const bool last = (out_final != nullptr);

    __shared__ alignas(16) __hip_bfloat16 Us[QT][DH + 8];      // u rows (attn out)
    __shared__ alignas(16) __hip_bfloat16 Pb[QT][NCH * 16 + 8];
    __shared__ alignas(16) __hip_bfloat16 Ebs[QT][DEMB + 8];   // bf16 res rows (A for qkv tail)
    __shared__ float statsA[QT][8];
    __shared__ float statsB[QT][8];

    // ---- e prefetch: 16 rows, wave owns cols [128w,128w+128); written by
    // the SAME tile in the previous launch -> issue all 32 loads at t=0.
    floatx4 eo8[8];
    #pragma unroll
    for (int n0 = 0; n0 < 8; n0++) {
        int col = wave * 128 + n0 * 16 + fr;
        #pragma unroll
        for (int r = 0; r < 4; r++)
            eo8[n0][r] = e[(size_t)(q0 + quad * 4 + r) * DEMB + col];
    }

    // ---- Q fragments straight from L2 (pre-scaled) ------------------------
    short8 af[4];
    #pragma unroll
    for (int kc = 0; kc < 4; kc++)
        af[kc] = *(const short8*)(Qb + (size_t)(q0 + fr) * DH + kc * 32 + kg);

    const int kstart = max(q0 - CWIN, 0);
    const int kend   = min(q0 + QT - 1 + CWIN + 1, NTOK);
    const int nch = (wave < 2) ? 5 : 4;   // chunks ch = wave + 8t, ch < 34

    // ---- scores: preload ALL K fragments, then MFMA -----------------------
    short8 kf[5][4];
    #pragma unroll
    for (int t = 0; t < 5; t++) {
        if (t >= nch) break;
        const __hip_bfloat16* krow = Kb + (size_t)(kstart + (wave + 8 * t) * 16 + fr) * DH;
        #pragma unroll
        for (int kc = 0; kc < 4; kc++)
            kf[t][kc] = *(const short8*)(krow + kc * 32 + kg);
    }
    floatx4 sreg[5];
    #pragma unroll
    for (int t = 0; t < 5; t++) {
        if (t >= nch) break;
        floatx4 s = {};
        #pragma unroll
        for (int kc = 0; kc < 4; kc++)
            s = __builtin_amdgcn_mfma_f32_16x16x32_bf16(af[kc], kf[t][kc], s, 0, 0, 0);
        sreg[t] = s;
    }

    // ---- band mask + per-row max ------------------------------------------
    float pmax[4] = {-1e30f, -1e30f, -1e30f, -1e30f};
    #pragma unroll
    for (int t = 0; t < 5; t++) {
        if (t >= nch) break;
        int tcol = kstart + (wave + 8 * t) * 16 + fr;
        #pragma unroll
        for (int r = 0; r < 4; r++) {
            int qg = q0 + quad * 4 + r;
            bool ok = (tcol < kend) && (tcol >= qg - CWIN) && (tcol < qg + CWIN);
            float v = ok ? sreg[t][r] : -1e30f;
            sreg[t][r] = v;
            pmax[r] = fmaxf(pmax[r], v);
        }
    }
    #pragma unroll
    for (int mm = 1; mm <= 8; mm <<= 1)
        #pragma unroll
        for (int r = 0; r < 4; r++) pmax[r] = fmaxf(pmax[r], __shfl_xor(pmax[r], mm, 64));
    if (fr == 0)
        #pragma unroll
        for (int r = 0; r < 4; r++) statsA[quad * 4 + r][wave] = pmax[r];
    __syncthreads();                                   // bar1: row maxes

    float M[4];
    #pragma unroll
    for (int r = 0; r < 4; r++) {
        int row = quad * 4 + r;
        float m = statsA[row][0];
        #pragma unroll
        for (int w = 1; w < 8; w++) m = fmaxf(m, statsA[row][w]);
        M[r] = m;
    }

    // ---- exp(s - M) -> Pb (A-layout), row sums ----------------------------
    float psum[4] = {};
    #pragma unroll
    for (int t = 0; t < 5; t++) {
        if (t >= nch) break;
        int colb = (wave + 8 * t) * 16 + fr;
        #pragma unroll
        for (int r = 0; r < 4; r++) {
            float p = __expf(sreg[t][r] - M[r]);
            psum[r] += p;
            Pb[quad * 4 + r][colb] = __float2bfloat16(p);
        }
    }
    #pragma unroll
    for (int mm = 1; mm <= 8; mm <<= 1)
        #pragma unroll
        for (int r = 0; r < 4; r++) psum[r] += __shfl_xor(psum[r], mm, 64);
    if (fr == 0)
        #pragma unroll
        for (int r = 0; r < 4; r++) statsB[quad * 4 + r][wave] = psum[r];
    __syncthreads();                                   // bar2: Pb + sums

    float linv[4];
    #pragma unroll
    for (int r = 0; r < 4; r++) {
        int row = quad * 4 + r;
        float s = statsB[row][0];
        #pragma unroll
        for (int w = 1; w < 8; w++) s += statsB[row][w];
        linv[r] = 1.0f / s;
    }

    // ---- PV: wave owns dims [16w,16w+16); 8-deep Vt fragment ring ---------
    {
        const __hip_bfloat16* vbase = Vtb + (size_t)(wave * 16 + fr) * NTOK + kstart + kg;
        short8 vf[8];
        #pragma unroll
        for (int i = 0; i < 8; i++) vf[i] = *(const short8*)(vbase + i * 32);
        floatx4 Of = {};
        #pragma unroll
        for (int kc = 0; kc < NCH / 2; kc++) {
            short8 pf = *(const short8*)&Pb[fr][kc * 32 + kg];
            short8 v = vf[kc & 7];
            if (kc + 8 < NCH / 2) vf[kc & 7] = *(const short8*)(vbase + (kc + 8) * 32);
            Of = __builtin_amdgcn_mfma_f32_16x16x32_bf16(pf, v, Of, 0, 0, 0);
        }
        int col = wave * 16 + fr;
        #pragma unroll
        for (int r = 0; r < 4; r++)
            Us[quad * 4 + r][col] = __float2bfloat16(Of[r] * linv[r]);
    }
    __syncthreads();                                   // bar3: u rows ready
    short8 af2[4];
    #pragma unroll
    for (int kc = 0; kc < 4; kc++) af2[kc] = *(const short8*)&Us[fr][kc * 32 + kg];

    // ---- out-proj: wave owns cols [128w,128w+128); 3-deep Wvu ring --------
    floatx4 accd[8] = {};
    {
        short8 wf[3][4];
        #pragma unroll
        for (int g = 0; g < 2; g++) {
            const __hip_bfloat16* wrow = Wvu + ((size_t)(wave * 128 + g * 16 + fr) << 7);
            #pragma unroll
            for (int kc = 0; kc < 4; kc++) wf[g][kc] = *(const short8*)(wrow + kc * 32 + kg);
        }
        #pragma unroll
        for (int n0 = 0; n0 < 8; n0++) {
            int cur = n0 % 3;
            if (n0 + 2 < 8) {
                int nx = (n0 + 2) % 3;
                const __hip_bfloat16* wrow = Wvu + ((size_t)(wave * 128 + (n0 + 2) * 16 + fr) << 7);
                #pragma unroll
                for (int kc = 0; kc < 4; kc++) wf[nx][kc] = *(const short8*)(wrow + kc * 32 + kg);
            }
            #pragma unroll
            for (int kc = 0; kc < 4; kc++)
                accd[n0] = __builtin_amdgcn_mfma_f32_16x16x32_bf16(af2[kc], wf[cur][kc],
                                                                  accd[n0], 0, 0, 0);
        }
    }

    // ---- norm stats (e rows already in registers) -------------------------
    float s1[4] = {}, s2[4] = {};
    #pragma unroll
    for (int n0 = 0; n0 < 8; n0++) {
        #pragma unroll
        for (int r = 0; r < 4; r++) {
            float od = eo8[n0][r] + accd[n0][r];
            s1[r] += od; s2[r] += od * od;
        }
    }
    #pragma unroll
    for (int mm = 1; mm <= 8; mm <<= 1)
        #pragma unroll
        for (int r = 0; r < 4; r++) {
            s1[r] += __shfl_xor(s1[r], mm, 64);
            s2[r] += __shfl_xor(s2[r], mm, 64);
        }
    if (fr == 0)
        #pragma unroll
        for (int r = 0; r < 4; r++) {
            statsA[quad * 4 + r][wave] = s1[r];
            statsB[quad * 4 + r][wave] = s2[r];
        }
    __syncthreads();                                   // bar4: norm stats

    float im0[4], mm_[4], isd[4];
    #pragma unroll
    for (int r = 0; r < 4; r++) {
        int row = quad * 4 + r;
        float S1 = statsA[row][0], S2 = statsB[row][0];
        #pragma unroll
        for (int w = 1; w < 8; w++) { S1 += statsA[row][w]; S2 += statsB[row][w]; }
        float m0 = S1 * (1.0f / DEMB);
        float iv = 1.0f / m0;
        float m  = m0 * iv;                        // mean(out/m0) ~ 1
        float st = S1 * iv;
        float var = (S2 * iv * iv - st * st * (1.0f / DEMB)) * (1.0f / (DEMB - 1));
        im0[r] = iv; mm_[r] = m; isd[r] = rsqrtf(var);
    }

    // ---- final residual+norm; write e (or out); stage bf16 res for tail ---
    #pragma unroll
    for (int n0 = 0; n0 < 8; n0++) {
        int col = wave * 128 + n0 * 16 + fr;
        #pragma unroll
        for (int r = 0; r < 4; r++) {
            float ev = eo8[n0][r];
            float t = (ev + accd[n0][r]) * im0[r];
            float res = ev + (t - mm_[r]) * isd[r] + mm_[r];
            size_t idx = (size_t)(q0 + quad * 4 + r) * DEMB + col;
            if (last) {
                out_final[idx] = res * 0.125f;
            } else {
                e[idx] = res;
                Ebs[quad * 4 + r][col] = __float2bfloat16(res);
            }
        }
    }

    // ---- fused next-head QKV: 24 N-tiles over 8 waves (3 each), -----------
    // 4-deep group ring (3 Wqkv fragments per k-group)
    if (!last) {
        __syncthreads();               // bar5: Ebs complete
        floatx4 acc3[3] = {};
        const int n0t = 3 * wave;
        const __hip_bfloat16* wbase = Wqkv_nxt + (size_t)(n0t * 16 + fr) * DEMB + kg;
        short8 bfr[4][3];
        #pragma unroll
        for (int g = 0; g < 3; g++)
            #pragma unroll
            for (int t = 0; t < 3; t++)
                bfr[g][t] = *(const short8*)(wbase + (size_t)t * 16 * DEMB + g * 32);
        #pragma unroll
        for (int kc = 0; kc < 32; kc++) {
            int cur = kc & 3;
            if (kc + 3 < 32) {
                int nx = (kc + 3) & 3;
                #pragma unroll
                for (int t = 0; t < 3; t++)
                    bfr[nx][t] = *(const short8*)(wbase + (size_t)t * 16 * DEMB + (kc + 3) * 32);
            }
            short8 a = *(const short8*)&Ebs[fr][kc * 32 + kg];
            #pragma unroll
            for (int t = 0; t < 3; t++)
                acc3[t] = __builtin_amdgcn_mfma_f32_16x16x32_bf16(a, bfr[cur][t],
                                                                  acc3[t], 0, 0, 0);
        }
        const int row0 = q0 + quad * 4;
        #pragma unroll
        for (int t = 0; t < 3; t++) {
            int n = n0t + t;
            if (n < 8) {               // Q, pre-scaled
                int col = n * 16 + fr;
                #pragma unroll
                for (int rr = 0; rr < 4; rr++)
                    Qn[(size_t)(row0 + rr) * DH + col] = __float2bfloat16(acc3[t][rr] * SCALE);
            } else if (n < 16) {       // K
                int col = (n - 8) * 16 + fr;
                #pragma unroll
                for (int rr = 0; rr < 4; rr++)
                    Kn[(size_t)(row0 + rr) * DH + col] = __float2bfloat16(acc3[t][rr]);
            } else {                   // V^T
                int d = (n - 16) * 16 + fr;
                union { __hip_bfloat16 h[4]; uint2 u; } p;
                #pragma unroll
                for (int rr = 0; rr < 4; rr++) p.h[rr] = __float2bfloat16(acc3[t][rr]);
                *(uint2*)(Vtn + (size_t)d * NTOK + row0) = p.u;
            }
        }
    }
}

extern "C" void kernel_launch(void* const* d_in, const int* in_sizes, int n_in,
                              void* d_out, int out_size, void* d_ws, size_t ws_size,
                              hipStream_t stream) {
    const float* x   = (const float*)d_in[0];
    const float* Wq  = (const float*)d_in[1];
    const float* Wk  = (const float*)d_in[2];
    const float* Wvd = (const float*)d_in[3];
    const float* Wvu = (const float*)d_in[4];

    char* ws = (char*)d_ws;
    float* e = (float*)ws;                                              // 16 MB
    __hip_bfloat16* ebf   = (__hip_bfloat16*)(ws + (16u << 20));        //  8 MB (head-0 prologue only)
    __hip_bfloat16* Qb[2] = {(__hip_bfloat16*)(ws + (24u << 20)),
                             (__hip_bfloat16*)(ws + (27u << 20))};      //  1 MB each
    __hip_bfloat16* Kb[2] = {(__hip_bfloat16*)(ws + (25u << 20)),
                             (__hip_bfloat16*)(ws + (28u << 20))};
    __hip_bfloat16* Vt[2] = {(__hip_bfloat16*)(ws + (26u << 20)),
                             (__hip_bfloat16*)(ws + (29u << 20))};
    __hip_bfloat16* wqkvb = (__hip_bfloat16*)(ws + (30u << 20));        //  6 MB
    __hip_bfloat16* wvub  = (__hip_bfloat16*)(ws + (36u << 20));        //  2 MB  -> 38 MB

    pack_wqkv<<<NH * QKVW * DEMB / 8 / 256, 256, 0, stream>>>(Wq, Wk, Wvd, wqkvb);
    pack_wvu<<<NH * DEMB * DH / 8 / 256, 256, 0, stream>>>(Wvu, wvub);
    init_e<<<NTOK * DEMB / 4 / 256, 256, 0, stream>>>((const float4*)x, (float4*)e, ebf);

    qkv_gemm_mfma<<<dim3(QKVW / 64, NTOK / 64), 256, 0, stream>>>(
        ebf, wqkvb, Qb[0], Kb[0], Vt[0]);

    for (int h = 0; h < NH; h++) {
        int cur = h & 1, nxt = 1 - cur;
        attn_head<<<NTOK / QT, 512, 0, stream>>>(
            Qb[cur], Kb[cur], Vt[cur],
            Qb[nxt], Kb[nxt], Vt[nxt],
            wqkvb + (size_t)((h + 1 < NH) ? h + 1 : 0) * QKVW * DEMB,
            wvub + (size_t)h * DEMB * DH, e,
            (h == NH - 1) ? (float*)d_out : nullptr);
    }
}

// Round 7
// 435.104 us; speedup vs baseline: 1.5944x; 1.0237x over previous
//
#include <hip/hip_runtime.h>
#include <hip/hip_bf16.h>

#define NTOK 4096
#define DEMB 1024
#define NH   8
#define DH   128
#define CWIN 256
#define QKVW 384
#define SCALE 0.08838834764831845f   // 1/sqrt(128)
#define QT 16
#define NCH 34                        // 16-key chunks covering the <=528-wide band

typedef __attribute__((ext_vector_type(8))) short short8;
typedef __attribute__((ext_vector_type(4))) float floatx4;

__device__ __forceinline__ short8 pack8(float4 a, float4 b) {
    union { __hip_bfloat16 h[8]; short8 v; } o;
    o.h[0] = __float2bfloat16(a.x); o.h[1] = __float2bfloat16(a.y);
    o.h[2] = __float2bfloat16(a.z); o.h[3] = __float2bfloat16(a.w);
    o.h[4] = __float2bfloat16(b.x); o.h[5] = __float2bfloat16(b.y);
    o.h[6] = __float2bfloat16(b.z); o.h[7] = __float2bfloat16(b.w);
    return o.v;
}

// ---------------- weight prep (once per call) ----------------
__global__ void pack_wqkv(const float* __restrict__ Wq, const float* __restrict__ Wk,
                          const float* __restrict__ Wvd, __hip_bfloat16* __restrict__ dst) {
    size_t base = ((size_t)blockIdx.x * 256 + threadIdx.x) * 8;
    int k = (int)(base & 1023);
    int rh = (int)(base >> 10);
    int h = rh / QKVW;
    int row = rh - h * QKVW;
    const float* srcs[3] = {Wq, Wk, Wvd};
    const float* s = srcs[row >> 7] + (((size_t)h * DH + (row & 127)) << 10) + k;
    *(short8*)(dst + base) = pack8(*(const float4*)s, *(const float4*)(s + 4));
}

__global__ void pack_wvu(const float* __restrict__ Wvu, __hip_bfloat16* __restrict__ dst) {
    size_t base = ((size_t)blockIdx.x * 256 + threadIdx.x) * 8;
    *(short8*)(dst + base) = pack8(*(const float4*)(Wvu + base), *(const float4*)(Wvu + base + 4));
}

// ---------------- stage 0: e = x (+ bf16 mirror) ---------------------------
__global__ void init_e(const float4* __restrict__ x, float4* __restrict__ e,
                       __hip_bfloat16* __restrict__ ebf) {
    int i = blockIdx.x * 256 + threadIdx.x;
    float4 v = x[i];
    e[i] = v;
    union { __hip_bfloat16 h[4]; uint2 u; } p;
    p.h[0] = __float2bfloat16(v.x); p.h[1] = __float2bfloat16(v.y);
    p.h[2] = __float2bfloat16(v.z); p.h[3] = __float2bfloat16(v.w);
    *(uint2*)(ebf + (size_t)i * 4) = p.u;
}

// ---------------- per-head qkv GEMM: emits Q (scaled), K, V^T --------------
// Reused for EVERY head now (de-fused from attn_head): reads the bf16
// mirror ebf (updated by attn_head each head), LDS-staged, 384 blocks ->
// real cross-block latency overlap (1.5 blocks/CU), unlike the fused tail.
__global__ __launch_bounds__(256) void qkv_gemm_mfma(const __hip_bfloat16* __restrict__ A,
                                                     const __hip_bfloat16* __restrict__ B,
                                                     __hip_bfloat16* __restrict__ Qb,
                                                     __hip_bfloat16* __restrict__ Kb,
                                                     __hip_bfloat16* __restrict__ Vtb) {
    constexpr int K = DEMB;
    constexpr int LDK = 40;
    const int c0 = blockIdx.x * 64, r0 = blockIdx.y * 64;
    const int tid = threadIdx.x;
    const int wave = tid >> 6, lane = tid & 63;
    const int wr = (wave >> 1) * 32, wc = (wave & 1) * 32;
    const int frow = lane & 15, kgrp = (lane >> 4) * 8;
    const int quad = lane >> 4;
    const int sr = tid >> 2, sk = (tid & 3) * 8;

    __shared__ __hip_bfloat16 As[64 * LDK];
    __shared__ __hip_bfloat16 Bs[64 * LDK];

    floatx4 acc[2][2] = {};

    for (int k0 = 0; k0 < K; k0 += 32) {
        __syncthreads();
        *(short8*)(As + sr * LDK + sk) = *(const short8*)(A + (size_t)(r0 + sr) * K + k0 + sk);
        *(short8*)(Bs + sr * LDK + sk) = *(const short8*)(B + (size_t)(c0 + sr) * K + k0 + sk);
        __syncthreads();
        short8 a0 = *(const short8*)(As + (wr + frow) * LDK + kgrp);
        short8 a1 = *(const short8*)(As + (wr + 16 + frow) * LDK + kgrp);
        short8 b0 = *(const short8*)(Bs + (wc + frow) * LDK + kgrp);
        short8 b1 = *(const short8*)(Bs + (wc + 16 + frow) * LDK + kgrp);
        acc[0][0] = __builtin_amdgcn_mfma_f32_16x16x32_bf16(a0, b0, acc[0][0], 0, 0, 0);
        acc[0][1] = __builtin_amdgcn_mfma_f32_16x16x32_bf16(a0, b1, acc[0][1], 0, 0, 0);
        acc[1][0] = __builtin_amdgcn_mfma_f32_16x16x32_bf16(a1, b0, acc[1][0], 0, 0, 0);
        acc[1][1] = __builtin_amdgcn_mfma_f32_16x16x32_bf16(a1, b1, acc[1][1], 0, 0, 0);
    }

    #pragma unroll
    for (int i = 0; i < 2; i++)
        #pragma unroll
        for (int j = 0; j < 2; j++) {
            int col = c0 + wc + j * 16 + frow;
            int row0 = r0 + wr + i * 16 + quad * 4;
            if (col < DH) {
                #pragma unroll
                for (int r = 0; r < 4; r++)
                    Qb[(size_t)(row0 + r) * DH + col] = __float2bfloat16(acc[i][j][r] * SCALE);
            } else if (col < 2 * DH) {
                #pragma unroll
                for (int r = 0; r < 4; r++)
                    Kb[(size_t)(row0 + r) * DH + col - DH] = __float2bfloat16(acc[i][j][r]);
            } else {
                union { __hip_bfloat16 h[4]; uint2 u; } p;
                #pragma unroll
                for (int r = 0; r < 4; r++) p.h[r] = __float2bfloat16(acc[i][j][r]);
                *(uint2*)(Vtb + (size_t)(col - 2 * DH) * NTOK + row0) = p.u;
            }
        }
}

// ---------------- fused head kernel (attention + out-proj + norm) ----------
// QT=16, grid 256, 8 waves. R6 established: runtime tracks VMEM count at
// ~300-580 cyc/load, near-serial; compiler won't pipeline this fused
// barrier-laced kernel (VGPR stayed at 80 despite a 256 cap + rings).
// So: REMOVE work instead. The next-head QKV tail (96 of ~200 loads/wave,
// zero cross-wave reuse) is de-fused to qkv_gemm_mfma; attn_head writes a
// bf16 mirror ebf for it (fire-and-forget stores). -33 KB LDS, -1 barrier.
// Max-subtraction kept (R4: mean drift -> |s| can exceed 88 by head 7).
// Q fragments direct from L2; 4 barriers/head.
// OOB band-edge fragment reads land in adjacent ws buffers: finite bf16,
// multiplied by p=0.
__global__ __launch_bounds__(512, 2) void attn_head(const __hip_bfloat16* __restrict__ Qb,
                                                    const __hip_bfloat16* __restrict__ Kb,
                                                    const __hip_bfloat16* __restrict__ Vtb,
                                                    __hip_bfloat16* __restrict__ ebf,
                                                    const __hip_bfloat16* __restrict__ Wvu,
                                                    float* __restrict__ e,
                                                    float* __restrict__ out_final) {
    // XCD-chunked swizzle: XCD k gets a contiguous run of 32 q-tiles so the
    // +-CWIN band and e-slice stay in its 4MB L2.
    const int tile = ((blockIdx.x & 7) << 5) | (blockIdx.x >> 3);
    const int q0 = tile * QT;
    const int tid = threadIdx.x;
    const int wave = tid >> 6, lane = tid & 63;       // wave in [0,8)
    const int fr = lane & 15, kg = (lane >> 4) * 8;
    const int quad = lane >> 4;
    const bool last = (out_final != nullptr);

    __shared__ alignas(16) __hip_bfloat16 Us[QT][DH + 8];      // u rows (attn out)
    __shared__ alignas(16) __hip_bfloat16 Pb[QT][NCH * 16 + 8];
    __shared__ float statsA[QT][8];
    __shared__ float statsB[QT][8];

    // ---- e prefetch: 16 rows, wave owns cols [128w,128w+128); written by
    // the SAME tile in the previous launch -> issue all 32 loads at t=0.
    floatx4 eo8[8];
    #pragma unroll
    for (int n0 = 0; n0 < 8; n0++) {
        int col = wave * 128 + n0 * 16 + fr;
        #pragma unroll
        for (int r = 0; r < 4; r++)
            eo8[n0][r] = e[(size_t)(q0 + quad * 4 + r) * DEMB + col];
    }

    // ---- Q fragments straight from L2 (pre-scaled) ------------------------
    short8 af[4];
    #pragma unroll
    for (int kc = 0; kc < 4; kc++)
        af[kc] = *(const short8*)(Qb + (size_t)(q0 + fr) * DH + kc * 32 + kg);

    const int kstart = max(q0 - CWIN, 0);
    const int kend   = min(q0 + QT - 1 + CWIN + 1, NTOK);
    const int nch = (wave < 2) ? 5 : 4;   // chunks ch = wave + 8t, ch < 34

    // ---- scores: preload K fragments, then MFMA ---------------------------
    short8 kf[5][4];
    #pragma unroll
    for (int t = 0; t < 5; t++) {
        if (t >= nch) break;
        const __hip_bfloat16* krow = Kb + (size_t)(kstart + (wave + 8 * t) * 16 + fr) * DH;
        #pragma unroll
        for (int kc = 0; kc < 4; kc++)
            kf[t][kc] = *(const short8*)(krow + kc * 32 + kg);
    }
    floatx4 sreg[5];
    #pragma unroll
    for (int t = 0; t < 5; t++) {
        if (t >= nch) break;
        floatx4 s = {};
        #pragma unroll
        for (int kc = 0; kc < 4; kc++)
            s = __builtin_amdgcn_mfma_f32_16x16x32_bf16(af[kc], kf[t][kc], s, 0, 0, 0);
        sreg[t] = s;
    }

    // ---- band mask + per-row max ------------------------------------------
    float pmax[4] = {-1e30f, -1e30f, -1e30f, -1e30f};
    #pragma unroll
    for (int t = 0; t < 5; t++) {
        if (t >= nch) break;
        int tcol = kstart + (wave + 8 * t) * 16 + fr;
        #pragma unroll
        for (int r = 0; r < 4; r++) {
            int qg = q0 + quad * 4 + r;
            bool ok = (tcol < kend) && (tcol >= qg - CWIN) && (tcol < qg + CWIN);
            float v = ok ? sreg[t][r] : -1e30f;
            sreg[t][r] = v;
            pmax[r] = fmaxf(pmax[r], v);
        }
    }
    #pragma unroll
    for (int mm = 1; mm <= 8; mm <<= 1)
        #pragma unroll
        for (int r = 0; r < 4; r++) pmax[r] = fmaxf(pmax[r], __shfl_xor(pmax[r], mm, 64));
    if (fr == 0)
        #pragma unroll
        for (int r = 0; r < 4; r++) statsA[quad * 4 + r][wave] = pmax[r];
    __syncthreads();                                   // bar1: row maxes

    float M[4];
    #pragma unroll
    for (int r = 0; r < 4; r++) {
        int row = quad * 4 + r;
        float m = statsA[row][0];
        #pragma unroll
        for (int w = 1; w < 8; w++) m = fmaxf(m, statsA[row][w]);
        M[r] = m;
    }

    // ---- exp(s - M) -> Pb (A-layout), row sums ----------------------------
    float psum[4] = {};
    #pragma unroll
    for (int t = 0; t < 5; t++) {
        if (t >= nch) break;
        int colb = (wave + 8 * t) * 16 + fr;
        #pragma unroll
        for (int r = 0; r < 4; r++) {
            float p = __expf(sreg[t][r] - M[r]);
            psum[r] += p;
            Pb[quad * 4 + r][colb] = __float2bfloat16(p);
        }
    }
    #pragma unroll
    for (int mm = 1; mm <= 8; mm <<= 1)
        #pragma unroll
        for (int r = 0; r < 4; r++) psum[r] += __shfl_xor(psum[r], mm, 64);
    if (fr == 0)
        #pragma unroll
        for (int r = 0; r < 4; r++) statsB[quad * 4 + r][wave] = psum[r];
    __syncthreads();                                   // bar2: Pb + sums

    float linv[4];
    #pragma unroll
    for (int r = 0; r < 4; r++) {
        int row = quad * 4 + r;
        float s = statsB[row][0];
        #pragma unroll
        for (int w = 1; w < 8; w++) s += statsB[row][w];
        linv[r] = 1.0f / s;
    }

    // ---- PV: wave owns dims [16w,16w+16); 8-deep Vt fragment ring ---------
    {
        const __hip_bfloat16* vbase = Vtb + (size_t)(wave * 16 + fr) * NTOK + kstart + kg;
        short8 vf[8];
        #pragma unroll
        for (int i = 0; i < 8; i++) vf[i] = *(const short8*)(vbase + i * 32);
        floatx4 Of = {};
        #pragma unroll
        for (int kc = 0; kc < NCH / 2; kc++) {
            short8 pf = *(const short8*)&Pb[fr][kc * 32 + kg];
            short8 v = vf[kc & 7];
            if (kc + 8 < NCH / 2) vf[kc & 7] = *(const short8*)(vbase + (kc + 8) * 32);
            Of = __builtin_amdgcn_mfma_f32_16x16x32_bf16(pf, v, Of, 0, 0, 0);
        }
        int col = wave * 16 + fr;
        #pragma unroll
        for (int r = 0; r < 4; r++)
            Us[quad * 4 + r][col] = __float2bfloat16(Of[r] * linv[r]);
    }
    __syncthreads();                                   // bar3: u rows ready
    short8 af2[4];
    #pragma unroll
    for (int kc = 0; kc < 4; kc++) af2[kc] = *(const short8*)&Us[fr][kc * 32 + kg];

    // ---- out-proj: wave owns cols [128w,128w+128); 3-deep Wvu ring --------
    floatx4 accd[8] = {};
    {
        short8 wf[3][4];
        #pragma unroll
        for (int g = 0; g < 2; g++) {
            const __hip_bfloat16* wrow = Wvu + ((size_t)(wave * 128 + g * 16 + fr) << 7);
            #pragma unroll
            for (int kc = 0; kc < 4; kc++) wf[g][kc] = *(const short8*)(wrow + kc * 32 + kg);
        }
        #pragma unroll
        for (int n0 = 0; n0 < 8; n0++) {
            int cur = n0 % 3;
            if (n0 + 2 < 8) {
                int nx = (n0 + 2) % 3;
                const __hip_bfloat16* wrow = Wvu + ((size_t)(wave * 128 + (n0 + 2) * 16 + fr) << 7);
                #pragma unroll
                for (int kc = 0; kc < 4; kc++) wf[nx][kc] = *(const short8*)(wrow + kc * 32 + kg);
            }
            #pragma unroll
            for (int kc = 0; kc < 4; kc++)
                accd[n0] = __builtin_amdgcn_mfma_f32_16x16x32_bf16(af2[kc], wf[cur][kc],
                                                                  accd[n0], 0, 0, 0);
        }
    }

    // ---- norm stats (e rows already in registers) -------------------------
    float s1[4] = {}, s2[4] = {};
    #pragma unroll
    for (int n0 = 0; n0 < 8; n0++) {
        #pragma unroll
        for (int r = 0; r < 4; r++) {
            float od = eo8[n0][r] + accd[n0][r];
            s1[r] += od; s2[r] += od * od;
        }
    }
    #pragma unroll
    for (int mm = 1; mm <= 8; mm <<= 1)
        #pragma unroll
        for (int r = 0; r < 4; r++) {
            s1[r] += __shfl_xor(s1[r], mm, 64);
            s2[r] += __shfl_xor(s2[r], mm, 64);
        }
    if (fr == 0)
        #pragma unroll
        for (int r = 0; r < 4; r++) {
            statsA[quad * 4 + r][wave] = s1[r];
            statsB[quad * 4 + r][wave] = s2[r];
        }
    __syncthreads();                                   // bar4: norm stats

    float im0[4], mm_[4], isd[4];
    #pragma unroll
    for (int r = 0; r < 4; r++) {
        int row = quad * 4 + r;
        float S1 = statsA[row][0], S2 = statsB[row][0];
        #pragma unroll
        for (int w = 1; w < 8; w++) { S1 += statsA[row][w]; S2 += statsB[row][w]; }
        float m0 = S1 * (1.0f / DEMB);
        float iv = 1.0f / m0;
        float m  = m0 * iv;                        // mean(out/m0) ~ 1
        float st = S1 * iv;
        float var = (S2 * iv * iv - st * st * (1.0f / DEMB)) * (1.0f / (DEMB - 1));
        im0[r] = iv; mm_[r] = m; isd[r] = rsqrtf(var);
    }

    // ---- final residual+norm; write e + bf16 mirror (or out) --------------
    #pragma unroll
    for (int n0 = 0; n0 < 8; n0++) {
        int col = wave * 128 + n0 * 16 + fr;
        #pragma unroll
        for (int r = 0; r < 4; r++) {
            float ev = eo8[n0][r];
            float t = (ev + accd[n0][r]) * im0[r];
            float res = ev + (t - mm_[r]) * isd[r] + mm_[r];
            size_t idx = (size_t)(q0 + quad * 4 + r) * DEMB + col;
            if (last) {
                out_final[idx] = res * 0.125f;
            } else {
                e[idx] = res;
                ebf[idx] = __float2bfloat16(res);
            }
        }
    }
}

extern "C" void kernel_launch(void* const* d_in, const int* in_sizes, int n_in,
                              void* d_out, int out_size, void* d_ws, size_t ws_size,
                              hipStream_t stream) {
    const float* x   = (const float*)d_in[0];
    const float* Wq  = (const float*)d_in[1];
    const float* Wk  = (const float*)d_in[2];
    const float* Wvd = (const float*)d_in[3];
    const float* Wvu = (const float*)d_in[4];

    char* ws = (char*)d_ws;
    float* e = (float*)ws;                                              // 16 MB
    __hip_bfloat16* ebf   = (__hip_bfloat16*)(ws + (16u << 20));        //  8 MB bf16 mirror of e
    __hip_bfloat16* Qb[2] = {(__hip_bfloat16*)(ws + (24u << 20)),
                             (__hip_bfloat16*)(ws + (27u << 20))};      //  1 MB each
    __hip_bfloat16* Kb[2] = {(__hip_bfloat16*)(ws + (25u << 20)),
                             (__hip_bfloat16*)(ws + (28u << 20))};
    __hip_bfloat16* Vt[2] = {(__hip_bfloat16*)(ws + (26u << 20)),
                             (__hip_bfloat16*)(ws + (29u << 20))};
    __hip_bfloat16* wqkvb = (__hip_bfloat16*)(ws + (30u << 20));        //  6 MB
    __hip_bfloat16* wvub  = (__hip_bfloat16*)(ws + (36u << 20));        //  2 MB  -> 38 MB

    pack_wqkv<<<NH * QKVW * DEMB / 8 / 256, 256, 0, stream>>>(Wq, Wk, Wvd, wqkvb);
    pack_wvu<<<NH * DEMB * DH / 8 / 256, 256, 0, stream>>>(Wvu, wvub);
    init_e<<<NTOK * DEMB / 4 / 256, 256, 0, stream>>>((const float4*)x, (float4*)e, ebf);

    // head-0 QKV from the x mirror
    qkv_gemm_mfma<<<dim3(QKVW / 64, NTOK / 64), 256, 0, stream>>>(
        ebf, wqkvb, Qb[0], Kb[0], Vt[0]);

    for (int h = 0; h < NH; h++) {
        int cur = h & 1, nxt = 1 - cur;
        attn_head<<<NTOK / QT, 512, 0, stream>>>(
            Qb[cur], Kb[cur], Vt[cur],
            ebf, wvub + (size_t)h * DEMB * DH, e,
            (h == NH - 1) ? (float*)d_out : nullptr);
        if (h + 1 < NH)   // de-fused next-head QKV (reads ebf written above)
            qkv_gemm_mfma<<<dim3(QKVW / 64, NTOK / 64), 256, 0, stream>>>(
                ebf, wqkvb + (size_t)(h + 1) * QKVW * DEMB,
                Qb[nxt], Kb[nxt], Vt[nxt]);
    }
}

// Round 8
// 427.683 us; speedup vs baseline: 1.6220x; 1.0174x over previous
//
#include <hip/hip_runtime.h>
#include <hip/hip_bf16.h>

#define NTOK 4096
#define DEMB 1024
#define NH   8
#define DH   128
#define CWIN 256
#define QKVW 384
#define SCALE 0.08838834764831845f   // 1/sqrt(128)
#define QT 16
#define NCH 34                        // 16-key chunks covering the <=528-wide band

typedef __attribute__((ext_vector_type(8))) short short8;
typedef __attribute__((ext_vector_type(4))) float floatx4;

__device__ __forceinline__ short8 pack8(float4 a, float4 b) {
    union { __hip_bfloat16 h[8]; short8 v; } o;
    o.h[0] = __float2bfloat16(a.x); o.h[1] = __float2bfloat16(a.y);
    o.h[2] = __float2bfloat16(a.z); o.h[3] = __float2bfloat16(a.w);
    o.h[4] = __float2bfloat16(b.x); o.h[5] = __float2bfloat16(b.y);
    o.h[6] = __float2bfloat16(b.z); o.h[7] = __float2bfloat16(b.w);
    return o.v;
}

// ---------------- weight prep (once per call) ----------------
__global__ void pack_wqkv(const float* __restrict__ Wq, const float* __restrict__ Wk,
                          const float* __restrict__ Wvd, __hip_bfloat16* __restrict__ dst) {
    size_t base = ((size_t)blockIdx.x * 256 + threadIdx.x) * 8;
    int k = (int)(base & 1023);
    int rh = (int)(base >> 10);
    int h = rh / QKVW;
    int row = rh - h * QKVW;
    const float* srcs[3] = {Wq, Wk, Wvd};
    const float* s = srcs[row >> 7] + (((size_t)h * DH + (row & 127)) << 10) + k;
    *(short8*)(dst + base) = pack8(*(const float4*)s, *(const float4*)(s + 4));
}

__global__ void pack_wvu(const float* __restrict__ Wvu, __hip_bfloat16* __restrict__ dst) {
    size_t base = ((size_t)blockIdx.x * 256 + threadIdx.x) * 8;
    *(short8*)(dst + base) = pack8(*(const float4*)(Wvu + base), *(const float4*)(Wvu + base + 4));
}

// ---------------- stage 0: e = x (+ bf16 mirror) ---------------------------
__global__ void init_e(const float4* __restrict__ x, float4* __restrict__ e,
                       __hip_bfloat16* __restrict__ ebf) {
    int i = blockIdx.x * 256 + threadIdx.x;
    float4 v = x[i];
    e[i] = v;
    union { __hip_bfloat16 h[4]; uint2 u; } p;
    p.h[0] = __float2bfloat16(v.x); p.h[1] = __float2bfloat16(v.y);
    p.h[2] = __float2bfloat16(v.z); p.h[3] = __float2bfloat16(v.w);
    *(uint2*)(ebf + (size_t)i * 4) = p.u;
}

// ---------------- per-head qkv GEMM: emits Q (scaled), K, V^T --------------
__global__ __launch_bounds__(256) void qkv_gemm_mfma(const __hip_bfloat16* __restrict__ A,
                                                     const __hip_bfloat16* __restrict__ B,
                                                     __hip_bfloat16* __restrict__ Qb,
                                                     __hip_bfloat16* __restrict__ Kb,
                                                     __hip_bfloat16* __restrict__ Vtb) {
    constexpr int K = DEMB;
    constexpr int LDK = 40;
    const int c0 = blockIdx.x * 64, r0 = blockIdx.y * 64;
    const int tid = threadIdx.x;
    const int wave = tid >> 6, lane = tid & 63;
    const int wr = (wave >> 1) * 32, wc = (wave & 1) * 32;
    const int frow = lane & 15, kgrp = (lane >> 4) * 8;
    const int quad = lane >> 4;
    const int sr = tid >> 2, sk = (tid & 3) * 8;

    __shared__ __hip_bfloat16 As[64 * LDK];
    __shared__ __hip_bfloat16 Bs[64 * LDK];

    floatx4 acc[2][2] = {};

    for (int k0 = 0; k0 < K; k0 += 32) {
        __syncthreads();
        *(short8*)(As + sr * LDK + sk) = *(const short8*)(A + (size_t)(r0 + sr) * K + k0 + sk);
        *(short8*)(Bs + sr * LDK + sk) = *(const short8*)(B + (size_t)(c0 + sr) * K + k0 + sk);
        __syncthreads();
        short8 a0 = *(const short8*)(As + (wr + frow) * LDK + kgrp);
        short8 a1 = *(const short8*)(As + (wr + 16 + frow) * LDK + kgrp);
        short8 b0 = *(const short8*)(Bs + (wc + frow) * LDK + kgrp);
        short8 b1 = *(const short8*)(Bs + (wc + 16 + frow) * LDK + kgrp);
        acc[0][0] = __builtin_amdgcn_mfma_f32_16x16x32_bf16(a0, b0, acc[0][0], 0, 0, 0);
        acc[0][1] = __builtin_amdgcn_mfma_f32_16x16x32_bf16(a0, b1, acc[0][1], 0, 0, 0);
        acc[1][0] = __builtin_amdgcn_mfma_f32_16x16x32_bf16(a1, b0, acc[1][0], 0, 0, 0);
        acc[1][1] = __builtin_amdgcn_mfma_f32_16x16x32_bf16(a1, b1, acc[1][1], 0, 0, 0);
    }

    #pragma unroll
    for (int i = 0; i < 2; i++)
        #pragma unroll
        for (int j = 0; j < 2; j++) {
            int col = c0 + wc + j * 16 + frow;
            int row0 = r0 + wr + i * 16 + quad * 4;
            if (col < DH) {
                #pragma unroll
                for (int r = 0; r < 4; r++)
                    Qb[(size_t)(row0 + r) * DH + col] = __float2bfloat16(acc[i][j][r] * SCALE);
            } else if (col < 2 * DH) {
                #pragma unroll
                for (int r = 0; r < 4; r++)
                    Kb[(size_t)(row0 + r) * DH + col - DH] = __float2bfloat16(acc[i][j][r]);
            } else {
                union { __hip_bfloat16 h[4]; uint2 u; } p;
                #pragma unroll
                for (int r = 0; r < 4; r++) p.h[r] = __float2bfloat16(acc[i][j][r]);
                *(uint2*)(Vtb + (size_t)(col - 2 * DH) * NTOK + row0) = p.u;
            }
        }
}

// ---------------- fused head kernel (attention + out-proj + norm) ----------
// R7 validated the serial-VMEM model (de-fuse -> faster). This round removes
// the 96 scalar VMEM ops/thread of the residual/norm phase: the out-proj
// delta crosses MFMA->linear layout through an XOR-swizzled f32 LDS bridge
// (P(c)=c^((c>>3)&7) on 16B chunks; <=4-way conflicts both sides; exact f32),
// then residual+norm+stores run in a linear mapping (thread t: row=t>>5,
// cols {j*128+(t&31)*4..+3}): e loads 32->8 float4, e stores 32->8, ebf
// stores 32->8 uint2, norm stats wave-local (no LDS stats barrier).
// Still 4 barriers/head. Max-subtraction kept (R4: mean drift -> |s|>88).
// OOB band-edge fragment reads land in adjacent ws buffers: finite bf16,
// multiplied by p=0.
__global__ __launch_bounds__(512, 2) void attn_head(const __hip_bfloat16* __restrict__ Qb,
                                                    const __hip_bfloat16* __restrict__ Kb,
                                                    const __hip_bfloat16* __restrict__ Vtb,
                                                    __hip_bfloat16* __restrict__ ebf,
                                                    const __hip_bfloat16* __restrict__ Wvu,
                                                    float* __restrict__ e,
                                                    float* __restrict__ out_final) {
    // XCD-chunked swizzle: XCD k gets a contiguous run of 32 q-tiles so the
    // +-CWIN band and e-slice stay in its 4MB L2.
    const int tile = ((blockIdx.x & 7) << 5) | (blockIdx.x >> 3);
    const int q0 = tile * QT;
    const int tid = threadIdx.x;
    const int wave = tid >> 6, lane = tid & 63;       // wave in [0,8)
    const int fr = lane & 15, kg = (lane >> 4) * 8;
    const int quad = lane >> 4;
    const bool last = (out_final != nullptr);

    __shared__ alignas(16) __hip_bfloat16 Us[QT][DH + 8];      // u rows (attn out)
    __shared__ alignas(16) __hip_bfloat16 Pb[QT][NCH * 16 + 8];
    __shared__ alignas(16) float Dls[QT * DEMB];               // delta bridge (swizzled)
    __shared__ float statsA[QT][8];
    __shared__ float statsB[QT][8];

    // ---- e prefetch in LINEAR mapping: thread owns row=tid>>5,
    // cols {j*128 + (tid&31)*4 .. +3}. Written by the SAME tile last launch.
    const int lrow = tid >> 5, l32 = tid & 31;
    floatx4 ev4[8];
    {
        const float* erow = e + (size_t)(q0 + lrow) * DEMB + l32 * 4;
        #pragma unroll
        for (int j = 0; j < 8; j++)
            ev4[j] = *(const floatx4*)(erow + j * 128);
    }

    // ---- Q fragments straight from L2 (pre-scaled) ------------------------
    short8 af[4];
    #pragma unroll
    for (int kc = 0; kc < 4; kc++)
        af[kc] = *(const short8*)(Qb + (size_t)(q0 + fr) * DH + kc * 32 + kg);

    const int kstart = max(q0 - CWIN, 0);
    const int kend   = min(q0 + QT - 1 + CWIN + 1, NTOK);
    const int nch = (wave < 2) ? 5 : 4;   // chunks ch = wave + 8t, ch < 34

    // ---- scores: preload K fragments, then MFMA ---------------------------
    short8 kf[5][4];
    #pragma unroll
    for (int t = 0; t < 5; t++) {
        if (t >= nch) break;
        const __hip_bfloat16* krow = Kb + (size_t)(kstart + (wave + 8 * t) * 16 + fr) * DH;
        #pragma unroll
        for (int kc = 0; kc < 4; kc++)
            kf[t][kc] = *(const short8*)(krow + kc * 32 + kg);
    }
    floatx4 sreg[5];
    #pragma unroll
    for (int t = 0; t < 5; t++) {
        if (t >= nch) break;
        floatx4 s = {};
        #pragma unroll
        for (int kc = 0; kc < 4; kc++)
            s = __builtin_amdgcn_mfma_f32_16x16x32_bf16(af[kc], kf[t][kc], s, 0, 0, 0);
        sreg[t] = s;
    }

    // ---- band mask + per-row max ------------------------------------------
    float pmax[4] = {-1e30f, -1e30f, -1e30f, -1e30f};
    #pragma unroll
    for (int t = 0; t < 5; t++) {
        if (t >= nch) break;
        int tcol = kstart + (wave + 8 * t) * 16 + fr;
        #pragma unroll
        for (int r = 0; r < 4; r++) {
            int qg = q0 + quad * 4 + r;
            bool ok = (tcol < kend) && (tcol >= qg - CWIN) && (tcol < qg + CWIN);
            float v = ok ? sreg[t][r] : -1e30f;
            sreg[t][r] = v;
            pmax[r] = fmaxf(pmax[r], v);
        }
    }
    #pragma unroll
    for (int mm = 1; mm <= 8; mm <<= 1)
        #pragma unroll
        for (int r = 0; r < 4; r++) pmax[r] = fmaxf(pmax[r], __shfl_xor(pmax[r], mm, 64));
    if (fr == 0)
        #pragma unroll
        for (int r = 0; r < 4; r++) statsA[quad * 4 + r][wave] = pmax[r];
    __syncthreads();                                   // bar1: row maxes

    float M[4];
    #pragma unroll
    for (int r = 0; r < 4; r++) {
        int row = quad * 4 + r;
        float m = statsA[row][0];
        #pragma unroll
        for (int w = 1; w < 8; w++) m = fmaxf(m, statsA[row][w]);
        M[r] = m;
    }

    // ---- exp(s - M) -> Pb (A-layout), row sums ----------------------------
    float psum[4] = {};
    #pragma unroll
    for (int t = 0; t < 5; t++) {
        if (t >= nch) break;
        int colb = (wave + 8 * t) * 16 + fr;
        #pragma unroll
        for (int r = 0; r < 4; r++) {
            float p = __expf(sreg[t][r] - M[r]);
            psum[r] += p;
            Pb[quad * 4 + r][colb] = __float2bfloat16(p);
        }
    }
    #pragma unroll
    for (int mm = 1; mm <= 8; mm <<= 1)
        #pragma unroll
        for (int r = 0; r < 4; r++) psum[r] += __shfl_xor(psum[r], mm, 64);
    if (fr == 0)
        #pragma unroll
        for (int r = 0; r < 4; r++) statsB[quad * 4 + r][wave] = psum[r];
    __syncthreads();                                   // bar2: Pb + sums

    float linv[4];
    #pragma unroll
    for (int r = 0; r < 4; r++) {
        int row = quad * 4 + r;
        float s = statsB[row][0];
        #pragma unroll
        for (int w = 1; w < 8; w++) s += statsB[row][w];
        linv[r] = 1.0f / s;
    }

    // ---- PV: wave owns dims [16w,16w+16); 8-deep Vt fragment ring ---------
    {
        const __hip_bfloat16* vbase = Vtb + (size_t)(wave * 16 + fr) * NTOK + kstart + kg;
        short8 vf[8];
        #pragma unroll
        for (int i = 0; i < 8; i++) vf[i] = *(const short8*)(vbase + i * 32);
        floatx4 Of = {};
        #pragma unroll
        for (int kc = 0; kc < NCH / 2; kc++) {
            short8 pf = *(const short8*)&Pb[fr][kc * 32 + kg];
            short8 v = vf[kc & 7];
            if (kc + 8 < NCH / 2) vf[kc & 7] = *(const short8*)(vbase + (kc + 8) * 32);
            Of = __builtin_amdgcn_mfma_f32_16x16x32_bf16(pf, v, Of, 0, 0, 0);
        }
        int col = wave * 16 + fr;
        #pragma unroll
        for (int r = 0; r < 4; r++)
            Us[quad * 4 + r][col] = __float2bfloat16(Of[r] * linv[r]);
    }
    __syncthreads();                                   // bar3: u rows ready
    short8 af2[4];
    #pragma unroll
    for (int kc = 0; kc < 4; kc++) af2[kc] = *(const short8*)&Us[fr][kc * 32 + kg];

    // ---- out-proj: wave owns cols [128w,128w+128); 3-deep Wvu ring --------
    floatx4 accd[8] = {};
    {
        short8 wf[3][4];
        #pragma unroll
        for (int g = 0; g < 2; g++) {
            const __hip_bfloat16* wrow = Wvu + ((size_t)(wave * 128 + g * 16 + fr) << 7);
            #pragma unroll
            for (int kc = 0; kc < 4; kc++) wf[g][kc] = *(const short8*)(wrow + kc * 32 + kg);
        }
        #pragma unroll
        for (int n0 = 0; n0 < 8; n0++) {
            int cur = n0 % 3;
            if (n0 + 2 < 8) {
                int nx = (n0 + 2) % 3;
                const __hip_bfloat16* wrow = Wvu + ((size_t)(wave * 128 + (n0 + 2) * 16 + fr) << 7);
                #pragma unroll
                for (int kc = 0; kc < 4; kc++) wf[nx][kc] = *(const short8*)(wrow + kc * 32 + kg);
            }
            #pragma unroll
            for (int kc = 0; kc < 4; kc++)
                accd[n0] = __builtin_amdgcn_mfma_f32_16x16x32_bf16(af2[kc], wf[cur][kc],
                                                                  accd[n0], 0, 0, 0);
        }
    }

    // ---- delta -> LDS bridge (MFMA layout writer, XOR-swizzled 16B chunks)
    #pragma unroll
    for (int n0 = 0; n0 < 8; n0++) {
        int c_w = wave * 32 + n0 * 4 + (fr >> 2);          // 16B chunk idx in row
        int pc  = c_w ^ ((c_w >> 3) & 7);                  // swizzle (involution)
        #pragma unroll
        for (int r = 0; r < 4; r++)
            Dls[((quad * 4 + r) << 10) + (pc << 2) + (fr & 3)] = accd[n0][r];
    }
    __syncthreads();                                   // bar4: delta ready

    // ---- residual + double-norm in LINEAR mapping -------------------------
    floatx4 dv4[8];
    float s1 = 0.0f, s2 = 0.0f;
    #pragma unroll
    for (int j = 0; j < 8; j++) {
        int c_r = j * 32 + l32;
        int pc  = c_r ^ ((c_r >> 3) & 7);
        floatx4 d = *(const floatx4*)&Dls[(lrow << 10) + (pc << 2)];
        dv4[j] = d;
        #pragma unroll
        for (int k = 0; k < 4; k++) {
            float od = ev4[j][k] + d[k];
            s1 += od; s2 += od * od;
        }
    }
    #pragma unroll
    for (int mm = 1; mm <= 16; mm <<= 1) {             // 32-lane row reduction
        s1 += __shfl_xor(s1, mm, 64);
        s2 += __shfl_xor(s2, mm, 64);
    }
    float m0 = s1 * (1.0f / DEMB);
    float iv = 1.0f / m0;
    float m  = m0 * iv;                                // mean(out/m0) ~ 1
    float st = s1 * iv;
    float var = (s2 * iv * iv - st * st * (1.0f / DEMB)) * (1.0f / (DEMB - 1));
    float isd = rsqrtf(var);

    // ---- final residual+norm; vectorized stores ---------------------------
    {
        float* eout = e + (size_t)(q0 + lrow) * DEMB + l32 * 4;
        __hip_bfloat16* ebout = ebf + (size_t)(q0 + lrow) * DEMB + l32 * 4;
        float* fout = last ? (out_final + (size_t)(q0 + lrow) * DEMB + l32 * 4) : nullptr;
        #pragma unroll
        for (int j = 0; j < 8; j++) {
            floatx4 res;
            #pragma unroll
            for (int k = 0; k < 4; k++) {
                float evv = ev4[j][k];
                float t = (evv + dv4[j][k]) * iv;
                res[k] = evv + (t - m) * isd + m;
            }
            if (last) {
                floatx4 ro = {res[0] * 0.125f, res[1] * 0.125f, res[2] * 0.125f, res[3] * 0.125f};
                *(floatx4*)(fout + j * 128) = ro;
            } else {
                *(floatx4*)(eout + j * 128) = res;
                union { __hip_bfloat16 h[4]; uint2 u; } p;
                #pragma unroll
                for (int k = 0; k < 4; k++) p.h[k] = __float2bfloat16(res[k]);
                *(uint2*)(ebout + j * 128) = p.u;
            }
        }
    }
}

extern "C" void kernel_launch(void* const* d_in, const int* in_sizes, int n_in,
                              void* d_out, int out_size, void* d_ws, size_t ws_size,
                              hipStream_t stream) {
    const float* x   = (const float*)d_in[0];
    const float* Wq  = (const float*)d_in[1];
    const float* Wk  = (const float*)d_in[2];
    const float* Wvd = (const float*)d_in[3];
    const float* Wvu = (const float*)d_in[4];

    char* ws = (char*)d_ws;
    float* e = (float*)ws;                                              // 16 MB
    __hip_bfloat16* ebf   = (__hip_bfloat16*)(ws + (16u << 20));        //  8 MB bf16 mirror of e
    __hip_bfloat16* Qb[2] = {(__hip_bfloat16*)(ws + (24u << 20)),
                             (__hip_bfloat16*)(ws + (27u << 20))};      //  1 MB each
    __hip_bfloat16* Kb[2] = {(__hip_bfloat16*)(ws + (25u << 20)),
                             (__hip_bfloat16*)(ws + (28u << 20))};
    __hip_bfloat16* Vt[2] = {(__hip_bfloat16*)(ws + (26u << 20)),
                             (__hip_bfloat16*)(ws + (29u << 20))};
    __hip_bfloat16* wqkvb = (__hip_bfloat16*)(ws + (30u << 20));        //  6 MB
    __hip_bfloat16* wvub  = (__hip_bfloat16*)(ws + (36u << 20));        //  2 MB  -> 38 MB

    pack_wqkv<<<NH * QKVW * DEMB / 8 / 256, 256, 0, stream>>>(Wq, Wk, Wvd, wqkvb);
    pack_wvu<<<NH * DEMB * DH / 8 / 256, 256, 0, stream>>>(Wvu, wvub);
    init_e<<<NTOK * DEMB / 4 / 256, 256, 0, stream>>>((const float4*)x, (float4*)e, ebf);

    // head-0 QKV from the x mirror
    qkv_gemm_mfma<<<dim3(QKVW / 64, NTOK / 64), 256, 0, stream>>>(
        ebf, wqkvb, Qb[0], Kb[0], Vt[0]);

    for (int h = 0; h < NH; h++) {
        int cur = h & 1, nxt = 1 - cur;
        attn_head<<<NTOK / QT, 512, 0, stream>>>(
            Qb[cur], Kb[cur], Vt[cur],
            ebf, wvub + (size_t)h * DEMB * DH, e,
            (h == NH - 1) ? (float*)d_out : nullptr);
        if (h + 1 < NH)   // de-fused next-head QKV (reads ebf written above)
            qkv_gemm_mfma<<<dim3(QKVW / 64, NTOK / 64), 256, 0, stream>>>(
                ebf, wqkvb + (size_t)(h + 1) * QKVW * DEMB,
                Qb[nxt], Kb[nxt], Vt[nxt]);
    }
}